// Round 10
// baseline (992.018 us; speedup 1.0000x reference)
//
#include <hip/hip_runtime.h>

#define H 181
#define T_LEN 1024
#define BB 16            // batch rows per block
#define NBLK 64          // 64 * 16 = 1024
#define NTHR 768         // 12 waves, 3 per SIMD
#define KT3 3            // k-tiles of 64 -> 192 >= 181
#define FRAGB 1024       // bytes per kt fragment (64 lanes x 16 B)
#define JP 192           // padded hidden dim
#define XST 1058         // x_s row stride

typedef __attribute__((ext_vector_type(4))) int   intx4;
typedef __attribute__((ext_vector_type(4))) float floatx4;
typedef __attribute__((ext_vector_type(2))) float floatx2;

#define LOG2E 1.4426950408889634f

// Schraudolph exp2 (balanced sawtooth, |rel err| <= ~3%), clamped to [-20,14]
#define SCH_C  1064992506.0f   // (127 - 0.043) * 2^23
#define SCH_LO 897220352.0f
#define SCH_HI 1182433024.0f

__device__ __forceinline__ float exp2_fast(float g) {
    float s = fmaf(g, 8388608.0f, SCH_C);
    s = fminf(fmaxf(s, SCH_LO), SCH_HI);
    return __uint_as_float((unsigned)s);
}
__device__ __forceinline__ float rcpf(float x) { return __builtin_amdgcn_rcpf(x); }
__device__ __forceinline__ float exp2f_hw(float x) { return __builtin_amdgcn_exp2f(x); }

// 64 persistent blocks x 16 batch, 12 waves (3/SIMD). INT8 datapath:
// A = per-row-scaled w_hh (i8, registers), B = h (i8, LDS, x127 fixed scale,
// valid since |h|<1 strictly). mfma_i32_16x16x64_i8: 9 MFMAs/wave/step (was
// 18 f16) -> MFMA pipe ~550 cy/step/CU; h frags halve -> 3 ds_read_b128.
// Dequant folds row-scale/127 and log2e into one fma per gate-unit. r-gate
// sigmoid via Schraudolph; z and n via exact v_exp_f32 (accuracy-critical).
// Grouped reciprocals: 1 rcp per 8 (r,z) + 1 per 4 (n). Exps clamped <=2^14
// so grouped products stay finite. Pad units carry zero A-weights.
__launch_bounds__(NTHR, 3)
__global__ void gru_mfma(const float* __restrict__ x,
                         const float* __restrict__ w_ih,
                         const float* __restrict__ w_hh,
                         const float* __restrict__ b_ih,
                         const float* __restrict__ b_hh,
                         const float* __restrict__ w_fc,
                         const float* __restrict__ b_fc,
                         float* __restrict__ out) {
    __shared__ __align__(16) char  hfr_s[2 * KT3 * FRAGB];   // 6 KB dbuf (i8)
    __shared__ float wsc_s[3][JP];                           // w_hh row scales
    __shared__ __align__(16) float x_s[16 * XST];            // x [bb][t]; reused for FC

    const int tid  = threadIdx.x;
    const int wv   = tid >> 6;
    const int lane = tid & 63;
    const int col  = lane & 15;
    const int q    = lane >> 4;
    const int b0   = blockIdx.x * BB;
    const int jt   = wv;

    // ---- A fragments: per-row int8-quantized w_hh, [gate][kt] ----
    // A[m = jt*16+col][k = kt*64 + q*16 + e], e = 0..15
    const int  mu = jt * 16 + col;
    const bool mv = (mu < H);
    intx4 afr[3][KT3];
    #pragma unroll
    for (int g = 0; g < 3; ++g) {
        const float* wrow = w_hh + (size_t)(g * H + (mv ? mu : 0)) * H;
        float rowmax = 0.0f;
        if (mv)
            for (int k = 0; k < H; ++k) rowmax = fmaxf(rowmax, fabsf(wrow[k]));
        float s    = (rowmax > 1e-30f) ? rowmax * (1.0f / 127.0f) : 1.0f;
        float invs = 1.0f / s;
        #pragma unroll
        for (int kt = 0; kt < KT3; ++kt) {
            union { signed char c[16]; intx4 v; } u;
            #pragma unroll
            for (int e = 0; e < 16; ++e) {
                int k = kt * 64 + q * 16 + e;
                float v = (mv && k < H) ? wrow[k] * invs : 0.0f;
                v = fminf(fmaxf(rintf(v), -127.0f), 127.0f);
                u.c[e] = (signed char)(int)v;
            }
            afr[g][kt] = u.v;
        }
        if (q == 0) wsc_s[g][mu] = s;   // one writer per (g,mu)
    }

    // ---- stage x coalesced into [bb][t]; zero h buffers ----
    for (int i = tid; i < BB * T_LEN; i += NTHR) {
        int bb = i >> 10, t = i & 1023;
        x_s[bb * XST + t] = x[(size_t)b0 * T_LEN + i];
    }
    {
        int* hz = (int*)hfr_s;
        for (int i = tid; i < 2 * KT3 * FRAGB / 4; i += NTHR) hz[i] = 0;
    }
    __syncthreads();

    // ---- per-lane unit params (units j0..j0+3); scales from LDS ----
    const int j0 = jt * 16 + q * 4;
    float dqR[4], dqZ[4], dqN[4];          // acc_i32 -> scaled pre-activation
    float wrS[4], wzS[4], wnS[4], baseR[4], baseZ[4], bnI[4], bhN[4];
    #pragma unroll
    for (int r = 0; r < 4; ++r) {
        int j = j0 + r;
        bool jv = (j < H);
        dqR[r] = -LOG2E * wsc_s[0][j] * (1.0f / 127.0f);
        dqZ[r] = -LOG2E * wsc_s[1][j] * (1.0f / 127.0f);
        dqN[r] = 2.0f * LOG2E * wsc_s[2][j] * (1.0f / 127.0f);
        wrS[r]   = jv ? -LOG2E * w_ih[j]                  : 0.0f;
        wzS[r]   = jv ? -LOG2E * w_ih[H + j]              : 0.0f;
        wnS[r]   = jv ?  2.0f * LOG2E * w_ih[2 * H + j]   : 0.0f;
        baseR[r] = jv ? -LOG2E * (b_ih[j] + b_hh[j])          : 0.0f;
        baseZ[r] = jv ? -LOG2E * (b_ih[H + j] + b_hh[H + j])  : 0.0f;
        bnI[r]   = jv ?  2.0f * LOG2E * b_ih[2 * H + j]   : 0.0f;
        bhN[r]   = jv ?  2.0f * LOG2E * b_hh[2 * H + j]   : 0.0f;
    }

    // ---- h write slot: 4 consecutive units as one b32 ----
    // unit j -> frag kt=j>>6, lane-slot l=((j>>4)&3)*16+col, byte e=j&15
    const int woffB = (j0 >> 6) * FRAGB + (((j0 >> 4) & 3) * 16 + col) * 16 + (q * 4);
    const int rbase = lane * 16;

    float h[4] = {0.f, 0.f, 0.f, 0.f};

    auto step = [&](const char* rb, char* wb, float xv) {
        intx4 bf[KT3];
        #pragma unroll
        for (int kt = 0; kt < KT3; ++kt)
            bf[kt] = *(const intx4*)(rb + kt * FRAGB + rbase);

        intx4 aR = {0, 0, 0, 0}, aZ = {0, 0, 0, 0}, aN = {0, 0, 0, 0};
        #pragma unroll
        for (int kt = 0; kt < KT3; ++kt) {
            aR = __builtin_amdgcn_mfma_i32_16x16x64_i8(afr[0][kt], bf[kt], aR, 0, 0, 0);
            aZ = __builtin_amdgcn_mfma_i32_16x16x64_i8(afr[1][kt], bf[kt], aZ, 0, 0, 0);
            aN = __builtin_amdgcn_mfma_i32_16x16x64_i8(afr[2][kt], bf[kt], aN, 0, 0, 0);
        }

        // ---- r (Schraudolph) and z (exact) denominators ----
        float d[8];
        #pragma unroll
        for (int r = 0; r < 4; ++r) {
            float gr = fmaf((float)aR[r], dqR[r], fmaf(xv, wrS[r], baseR[r]));
            d[r] = 1.0f + exp2_fast(gr);
        }
        #pragma unroll
        for (int r = 0; r < 4; ++r) {
            float gz = fmaf((float)aZ[r], dqZ[r], fmaf(xv, wzS[r], baseZ[r]));
            d[4 + r] = 1.0f + exp2f_hw(fminf(gz, 14.0f));
        }
        // grouped inversion of 8 (1 v_rcp)
        float p[8];
        p[0] = d[0];
        #pragma unroll
        for (int i = 1; i < 8; ++i) p[i] = p[i - 1] * d[i];
        float qv = rcpf(p[7]);
        float inv[8];
        #pragma unroll
        for (int i = 7; i >= 1; --i) {
            inv[i] = qv * p[i - 1];
            qv = qv * d[i];
        }
        inv[0] = qv;

        // ---- n gate (exact exp), grouped-4 inversion ----
        float dn[4];
        #pragma unroll
        for (int r = 0; r < 4; ++r) {
            float ghn = fmaf((float)aN[r], dqN[r], bhN[r]);     // 2*log2e*(hh+b_hh)
            float gn  = fmaf(inv[r], ghn, fmaf(xv, wnS[r], bnI[r]));
            dn[r] = 1.0f + exp2f_hw(fminf(gn, 14.0f));
        }
        float pn1 = dn[0] * dn[1], pn2 = pn1 * dn[2], pn3 = pn2 * dn[3];
        float qn = rcpf(pn3);
        float rn[4];
        rn[3] = qn * pn2;  qn *= dn[3];
        rn[2] = qn * pn1;  qn *= dn[2];
        rn[1] = qn * dn[0];
        rn[0] = qn * dn[1];

        int iq[4];
        #pragma unroll
        for (int r = 0; r < 4; ++r) {
            float nn = fmaf(-2.0f, rn[r], 1.0f);       // tanh
            h[r] = fmaf(inv[4 + r], h[r] - nn, nn);    // n + z*(h-n); |h|<1
            iq[r] = (int)rintf(h[r] * 127.0f);
        }
        unsigned pk = (iq[0] & 255) | ((iq[1] & 255) << 8) |
                      ((iq[2] & 255) << 16) | ((unsigned)iq[3] << 24);
        *(unsigned*)(wb + woffB) = pk;
        __syncthreads();
    };

    const float* xrow = &x_s[col * XST];
    char* buf0 = hfr_s;
    char* buf1 = hfr_s + KT3 * FRAGB;
    for (int t = 0; t < T_LEN; t += 2) {
        floatx2 xv2 = *(const floatx2*)&xrow[t];
        step(buf0, buf1, xv2[0]);
        step(buf1, buf0, xv2[1]);
    }

    // ---- final FC; reuse x_s as fp32 h buffer ----
    float* hfin = x_s;
    floatx4 hv = {h[0], h[1], h[2], h[3]};
    *(floatx4*)&hfin[col * JP + j0] = hv;
    __syncthreads();
    if (tid < BB * 10) {
        int bb = tid / 10, c = tid % 10;
        float acc = b_fc[c];
        for (int k = 0; k < H; ++k)
            acc = fmaf(hfin[bb * JP + k], w_fc[c * H + k], acc);
        out[(b0 + bb) * 10 + c] = acc;
    }
}

extern "C" void kernel_launch(void* const* d_in, const int* in_sizes, int n_in,
                              void* d_out, int out_size, void* d_ws, size_t ws_size,
                              hipStream_t stream) {
    const float* x    = (const float*)d_in[0];
    const float* w_ih = (const float*)d_in[1];
    const float* w_hh = (const float*)d_in[2];
    const float* b_ih = (const float*)d_in[3];
    const float* b_hh = (const float*)d_in[4];
    const float* w_fc = (const float*)d_in[5];
    const float* b_fc = (const float*)d_in[6];
    float* out = (float*)d_out;

    gru_mfma<<<NBLK, NTHR, 0, stream>>>(x, w_ih, w_hh, b_ih, b_hh, w_fc, b_fc, out);
}